// Round 7
// baseline (448.401 us; speedup 1.0000x reference)
//
#include <hip/hip_runtime.h>
#include <math.h>

#define B 8
#define C 512
#define K 19
#define HW 16384
#define ROWS (B * K)             // 152
#define L2E 1.44269504088896340736f

// softmax two-phase config
#define NSEG 8
#define SEG (HW / NSEG)          // 2048 elements per segment

// gather config
#define CPW 4                    // c-rows per wave -> acc[4][19] = 76 VGPRs
#define NSC 4                    // s-chunks per row
#define SCHUNK (HW / NSC)        // 4096 s per wave
#define TS 256                   // s per step (64 lanes x float4)
#define NT (SCHUNK / TS)         // 16 steps

// Phase A: per-(row,segment) partial softmax stats.
__global__ __launch_bounds__(256)
void softmax_partial_kernel(const float* __restrict__ aux, float* __restrict__ partials) {
    int blk = blockIdx.x;                  // 0 .. ROWS*NSEG-1
    int row = blk >> 3;
    int seg = blk & (NSEG - 1);
    const float4* x4 = (const float4*)(aux + (size_t)row * HW + seg * SEG);
    int tid  = threadIdx.x;
    int lane = tid & 63;
    int wave = tid >> 6;
    __shared__ float red[4];

    float4 v0 = x4[tid];
    float4 v1 = x4[tid + 256];
    float m = fmaxf(fmaxf(fmaxf(v0.x, v0.y), fmaxf(v0.z, v0.w)),
                    fmaxf(fmaxf(v1.x, v1.y), fmaxf(v1.z, v1.w)));
    #pragma unroll
    for (int off = 32; off > 0; off >>= 1) m = fmaxf(m, __shfl_xor(m, off, 64));
    if (lane == 0) red[wave] = m;
    __syncthreads();
    m = fmaxf(fmaxf(red[0], red[1]), fmaxf(red[2], red[3]));
    __syncthreads();

    float s = exp2f((v0.x - m) * L2E) + exp2f((v0.y - m) * L2E)
            + exp2f((v0.z - m) * L2E) + exp2f((v0.w - m) * L2E)
            + exp2f((v1.x - m) * L2E) + exp2f((v1.y - m) * L2E)
            + exp2f((v1.z - m) * L2E) + exp2f((v1.w - m) * L2E);
    #pragma unroll
    for (int off = 32; off > 0; off >>= 1) s += __shfl_xor(s, off, 64);
    if (lane == 0) red[wave] = s;
    __syncthreads();
    if (tid == 0) {
        partials[blk * 2]     = m;
        partials[blk * 2 + 1] = red[0] + red[1] + red[2] + red[3];
    }
}

// Phase B: combine NSEG partials per row. Emits ONE coef per row:
// coef = -m*log2e - log2(Z), so p = exp2(fma(a, log2e, coef)) = e^(a-m)/Z.
__global__ __launch_bounds__(256)
void softmax_combine_kernel(const float* __restrict__ partials, float* __restrict__ stats) {
    int row = threadIdx.x;
    if (row < ROWS) {
        float mj[NSEG], zj[NSEG];
        float m = -INFINITY;
        #pragma unroll
        for (int j = 0; j < NSEG; j++) {
            mj[j] = partials[(row * NSEG + j) * 2];
            zj[j] = partials[(row * NSEG + j) * 2 + 1];
            m = fmaxf(m, mj[j]);
        }
        float Z = 0.f;
        #pragma unroll
        for (int j = 0; j < NSEG; j++) Z += zj[j] * exp2f((mj[j] - m) * L2E);
        stats[row] = -m * L2E - log2f(Z);
    }
}

// Gather: fully independent waves, NO LDS, NO barriers (R6 showed the LDS
// pipe at ~5.4K cyc/CU/tile was the bottleneck and barriers aligned stalls;
// L1 serves the cross-wave aux re-reads for free). Each wave: 4 c-rows x one
// 4096-s chunk; probs recomputed per-wave with invz folded into coef.
// ALLOCATOR LAW (R1-R5): VGPR budget = 512/(2*declared_min_waves_per_eu);
// waves_per_eu(2) -> 128 VGPRs, live set ~124. Do NOT declare 4 (-> 64, spill).
__global__ __launch_bounds__(256)
__attribute__((amdgpu_waves_per_eu(2)))
void gather_kernel(const float* __restrict__ feats, const float* __restrict__ aux,
                   const float* __restrict__ stats, float* __restrict__ out) {
    int wid  = blockIdx.x * 4 + (threadIdx.x >> 6);   // 0 .. 4095
    int lane = threadIdx.x & 63;
    // block = (b, sc, 4 consecutive c-groups): the 4 waves share aux tiles (L1)
    int cg = wid & 127;
    int sc = (wid >> 7) & (NSC - 1);
    int b  = wid >> 9;
    int c0 = cg * CPW;

    const float* Abase = aux   + (size_t)b * K * HW + sc * SCHUNK;
    const float* Fbase = feats + ((size_t)b * C + c0) * HW + sc * SCHUNK;

    // coef -> SGPRs (wave-uniform)
    float coef[K];
    #pragma unroll
    for (int k = 0; k < K; k++)
        coef[k] = __int_as_float(__builtin_amdgcn_readfirstlane(__float_as_int(stats[b * K + k])));

    float acc[CPW][K];
    #pragma unroll
    for (int c = 0; c < CPW; c++)
        #pragma unroll
        for (int k = 0; k < K; k++) acc[c][k] = 0.f;

    float4 f_cur[CPW], f_next[CPW];
    #pragma unroll
    for (int c = 0; c < CPW; c++)
        f_cur[c] = *(const float4*)(Fbase + c * HW + lane * 4);

    for (int t = 0; t < NT; t++) {
        int s0 = t * TS + lane * 4;
        // feats prefetch one step ahead (full k-loop of latency distance)
        if (t + 1 < NT) {
            #pragma unroll
            for (int c = 0; c < CPW; c++)
                f_next[c] = *(const float4*)(Fbase + c * HW + s0 + TS);
        }
        // aux pipelined at distance 1 (a0/a1 rotation keeps 2 float4 live)
        float4 a0 = *(const float4*)(Abase + s0);
        #pragma unroll
        for (int k = 0; k < K; k++) {
            float4 a1;
            if (k + 1 < K) a1 = *(const float4*)(Abase + (k + 1) * HW + s0);
            float4 p;
            p.x = exp2f(fmaf(a0.x, L2E, coef[k]));
            p.y = exp2f(fmaf(a0.y, L2E, coef[k]));
            p.z = exp2f(fmaf(a0.z, L2E, coef[k]));
            p.w = exp2f(fmaf(a0.w, L2E, coef[k]));
            #pragma unroll
            for (int c = 0; c < CPW; c++) {
                acc[c][k] = fmaf(p.x, f_cur[c].x, acc[c][k]);
                acc[c][k] = fmaf(p.y, f_cur[c].y, acc[c][k]);
                acc[c][k] = fmaf(p.z, f_cur[c].z, acc[c][k]);
                acc[c][k] = fmaf(p.w, f_cur[c].w, acc[c][k]);
            }
            a0 = a1;
        }
        #pragma unroll
        for (int c = 0; c < CPW; c++) f_cur[c] = f_next[c];
    }

    // butterfly reduce over 64 lanes, one atomic per (c,k) per wave
    #pragma unroll
    for (int c = 0; c < CPW; c++)
        #pragma unroll
        for (int k = 0; k < K; k++) {
            float v = acc[c][k];
            #pragma unroll
            for (int off = 32; off > 0; off >>= 1) v += __shfl_xor(v, off, 64);
            if (lane == 0)
                atomicAdd(&out[((size_t)b * C + c0 + c) * K + k], v);
        }
}

extern "C" void kernel_launch(void* const* d_in, const int* in_sizes, int n_in,
                              void* d_out, int out_size, void* d_ws, size_t ws_size,
                              hipStream_t stream) {
    const float* feats = (const float*)d_in[0];   // bb_feats [8,512,128,128]
    const float* aux   = (const float*)d_in[1];   // aux_out  [8,19,128,128]
    float* out      = (float*)d_out;              // [8,512,19,1]
    float* stats    = (float*)d_ws;               // 152 floats (coef per row)
    float* partials = (float*)d_ws + 512;         // 152*8*2 floats

    hipMemsetAsync(d_out, 0, (size_t)out_size * sizeof(float), stream);
    softmax_partial_kernel<<<ROWS * NSEG, 256, 0, stream>>>(aux, partials);
    softmax_combine_kernel<<<1, 256, 0, stream>>>(partials, stats);
    gather_kernel<<<(B * (C / CPW) * NSC) / 4, 256, 0, stream>>>(feats, aux, stats, out);
}